// Round 3
// baseline (731.937 us; speedup 1.0000x reference)
//
#include <hip/hip_runtime.h>
#include <hip/hip_bf16.h>

#define E_DIM 1024
#define HDIM  2730
#define HP    2816   // H padded to multiple of 128
#define NEXP  8
#define NTOK  4096
#define NPAIR 8192
#define NSLOT 72     // max m-tiles of 128 over all experts (<=71) + pad
#define LN_EPS 1e-5f

typedef __attribute__((ext_vector_type(8))) short  short8;
typedef __attribute__((ext_vector_type(4))) short  short4v;
typedef __attribute__((ext_vector_type(4))) float  floatx4;
typedef __attribute__((ext_vector_type(4))) int    intx4;

__device__ __forceinline__ __hip_bfloat16 f2bf(float f) { return __float2bfloat16(f); }

// async global->LDS, 16B per lane; LDS dest = wave-uniform base + lane*16
__device__ __forceinline__ void gload16(const __hip_bfloat16* g, __hip_bfloat16* l) {
  __builtin_amdgcn_global_load_lds(
      (const __attribute__((address_space(1))) void*)(g),
      (__attribute__((address_space(3))) void*)(l), 16, 0, 0);
}

// ---------------- router: fp32 logits, top-2, softmax weights ----------------
__global__ __launch_bounds__(256) void router_k(const float* __restrict__ x,
    const float* __restrict__ Wr, int* __restrict__ counts,
    int* __restrict__ tk_idx, float* __restrict__ tk_w) {
  int wid = threadIdx.x >> 6, lane = threadIdx.x & 63;
  int t = blockIdx.x * 4 + wid;
  const float* xr = x + (size_t)t * E_DIM;
  float xv[16];
#pragma unroll
  for (int i = 0; i < 16; ++i) xv[i] = xr[lane + 64 * i];
  float lg[8];
#pragma unroll
  for (int e = 0; e < 8; ++e) {
    const float* wr = Wr + e * E_DIM;
    float a = 0.f;
#pragma unroll
    for (int i = 0; i < 16; ++i) a += xv[i] * wr[lane + 64 * i];
#pragma unroll
    for (int o = 32; o; o >>= 1) a += __shfl_xor(a, o, 64);
    lg[e] = a;
  }
  if (lane == 0) {
    int i0 = 0; float l0 = lg[0];
#pragma unroll
    for (int e = 1; e < 8; ++e) if (lg[e] > l0) { l0 = lg[e]; i0 = e; }
    int i1 = -1; float l1 = -1e30f;
#pragma unroll
    for (int e = 0; e < 8; ++e) if (e != i0 && lg[e] > l1) { l1 = lg[e]; i1 = e; }
    float w0 = 1.f / (1.f + __expf(l1 - l0));
    atomicAdd(&counts[i0], 1);
    atomicAdd(&counts[i1], 1);
    tk_idx[2 * t]     = i0;  tk_idx[2 * t + 1] = i1;
    tk_w[2 * t]       = w0;  tk_w[2 * t + 1]   = 1.f - w0;
  }
}

// offsets + compact (expert, m0) tile table: active slots contiguous from 0.
__global__ void offsets_k(const int* __restrict__ counts, int* __restrict__ offsets,
                          int* __restrict__ cursor,
                          int* __restrict__ slot_e, int* __restrict__ slot_m0) {
  if (threadIdx.x == 0) {
    int off = 0, s = 0;
    for (int e = 0; e < NEXP; ++e) {
      offsets[e] = off; cursor[e] = off;
      for (int m0 = 0; m0 < counts[e]; m0 += 128) { slot_e[s] = e; slot_m0[s] = m0; ++s; }
      off += counts[e];
    }
    for (; s < NSLOT; ++s) { slot_e[s] = -1; slot_m0[s] = 0; }
  }
}

__global__ __launch_bounds__(256) void scatter_k(const int* __restrict__ tk_idx,
    const float* __restrict__ tk_w, int* __restrict__ cursor,
    int* __restrict__ pair_token, float* __restrict__ pair_w, int* __restrict__ pair_pos) {
  int t = blockIdx.x * 256 + threadIdx.x;
#pragma unroll
  for (int k = 0; k < 2; ++k) {
    int e = tk_idx[2 * t + k];
    int pos = atomicAdd(&cursor[e], 1);
    pair_token[pos] = t;
    pair_w[pos] = tk_w[2 * t + k];
    pair_pos[2 * t + k] = pos;
  }
}

// ---------------- expert-sorted token rows: xs[p] = bf16(x[pair_token[p]]) ----------------
__global__ __launch_bounds__(256) void gatherx_k(const float* __restrict__ x,
    const int* __restrict__ pair_token, __hip_bfloat16* __restrict__ xs) {
  int p = blockIdx.x;
  int t = pair_token[p];
  const float* src = x + (size_t)t * E_DIM;
  __hip_bfloat16* dst = xs + (size_t)p * E_DIM;
  int i = threadIdx.x * 4;
  floatx4 v = *(const floatx4*)(src + i);
  union { __hip_bfloat16 h[4]; short4v s; } u;
#pragma unroll
  for (int j = 0; j < 4; ++j) u.h[j] = f2bf(v[j]);
  *(short4v*)(dst + i) = u.s;
}

// ------------- transpose + convert: in fp32 [R][C] -> out bf16 [Cp][outRS] -------------
__global__ __launch_bounds__(256) void tcvt_k(const float* __restrict__ in,
    __hip_bfloat16* __restrict__ out, int R, int C, int outRS,
    size_t inExpStride, size_t outExpStride) {
  __shared__ float tile[64 * 65];
  int e = blockIdx.z;
  const float* ip = in + inExpStride * e;
  __hip_bfloat16* op = out + outExpStride * e;
  int c0 = blockIdx.x * 64, r0 = blockIdx.y * 64;
#pragma unroll
  for (int i = 0; i < 16; ++i) {
    int idx = i * 256 + threadIdx.x;
    int rr = idx >> 6, cc = idx & 63;
    int gr = r0 + rr, gc = c0 + cc;
    tile[rr * 65 + cc] = (gr < R && gc < C) ? ip[(size_t)gr * C + gc] : 0.f;
  }
  __syncthreads();
#pragma unroll
  for (int i = 0; i < 2; ++i) {
    int idx = i * 256 + threadIdx.x;
    int cc = idx >> 3, rb = (idx & 7) * 8;
    union { __hip_bfloat16 h[8]; intx4 v; } u;
#pragma unroll
    for (int j = 0; j < 8; ++j) u.h[j] = f2bf(tile[(rb + j) * 65 + cc]);
    *(intx4*)(op + (size_t)(c0 + cc) * outRS + (r0 + rb)) = u.v;
  }
}

// ---------------- GEMM1: h = silu(xs@Wv+bv) * (xs@Wg+bg) ----------------
// 128m x 128n block (dual B), BK=32, 2-phase double-buffered LDS (T3 minimum):
// STAGE(t+1) issued before COMPUTE(t); one __syncthreads per K-step drains the
// overlapped loads. XOR-4-chunk swizzle on 64B rows (pre-swizzled source).
__global__ __launch_bounds__(256, 2) void gemm1_k(
    const __hip_bfloat16* __restrict__ xs,
    const int* __restrict__ counts, const int* __restrict__ offsets,
    const int* __restrict__ slot_e, const int* __restrict__ slot_m0,
    const float* __restrict__ bv, const float* __restrict__ bg,
    const __hip_bfloat16* __restrict__ WvT, const __hip_bfloat16* __restrict__ WgT,
    __hip_bfloat16* __restrict__ h) {
  int slot = blockIdx.y;
  int e = slot_e[slot];
  if (e < 0) return;
  int m0 = slot_m0[slot];
  int Me = counts[e], off = offsets[e];
  int n0 = blockIdx.x * 128;

  __shared__ __align__(16) __hip_bfloat16 sA[2][128 * 32];
  __shared__ __align__(16) __hip_bfloat16 sBv[2][128 * 32];
  __shared__ __align__(16) __hip_bfloat16 sBg[2][128 * 32];

  int tid = threadIdx.x;
  int wid = tid >> 6, lane = tid & 63;
  int wm = wid >> 1, wn = wid & 1;
  int q = lane >> 4, r = lane & 15;

  // fragment read offsets (halfs): row*32 + ((q ^ (row&3))<<3), row&3 == r&3
  int csw = (q ^ (r & 3)) << 3;
  int aoff[4], boff[4];
#pragma unroll
  for (int mi = 0; mi < 4; ++mi) aoff[mi] = (wm * 64 + mi * 16 + r) * 32 + csw;
#pragma unroll
  for (int ni = 0; ni < 4; ++ni) boff[ni] = (wn * 64 + ni * 16 + r) * 32 + csw;

  // staging: each gload16 covers 16 rows x 64B. lane l -> row l>>2, lds chunk
  // l&3; source chunk = (l&3) ^ ((l>>2)&3). Wave wid + i*4 covers row group.
  int srow4   = lane >> 2;
  int schunk4 = (lane & 3) ^ (srow4 & 3);
  const __hip_bfloat16* gA = xs + (size_t)(off + m0 + wid * 16 + srow4) * E_DIM + schunk4 * 8;
  size_t wb = (size_t)e * ((size_t)HP * E_DIM);
  size_t browoff = wb + (size_t)(n0 + wid * 16 + srow4) * E_DIM + schunk4 * 8;
  const __hip_bfloat16* gv = WvT + browoff;
  const __hip_bfloat16* gg = WgT + browoff;

  floatx4 accv[4][4], accg[4][4];
  floatx4 zz = {0.f, 0.f, 0.f, 0.f};
#pragma unroll
  for (int mi = 0; mi < 4; ++mi)
#pragma unroll
    for (int ni = 0; ni < 4; ++ni) { accv[mi][ni] = zz; accg[mi][ni] = zz; }

#define G1_STAGE(BUF)                                                          \
  {                                                                            \
    _Pragma("unroll")                                                          \
    for (int i = 0; i < 2; ++i) {                                              \
      gload16(gA + (size_t)i * 64 * E_DIM, &sA[BUF][(wid + i * 4) * 512]);     \
      gload16(gv + (size_t)i * 64 * E_DIM, &sBv[BUF][(wid + i * 4) * 512]);    \
      gload16(gg + (size_t)i * 64 * E_DIM, &sBg[BUF][(wid + i * 4) * 512]);    \
    }                                                                          \
    gA += 32; gv += 32; gg += 32;                                              \
  }

#define G1_COMPUTE(BUF)                                                        \
  {                                                                            \
    short8 av[4];                                                              \
    _Pragma("unroll")                                                          \
    for (int mi = 0; mi < 4; ++mi)                                             \
      av[mi] = *(const short8*)(&sA[BUF][aoff[mi]]);                           \
    _Pragma("unroll")                                                          \
    for (int ni = 0; ni < 4; ++ni) {                                           \
      short8 b8v = *(const short8*)(&sBv[BUF][boff[ni]]);                      \
      short8 b8g = *(const short8*)(&sBg[BUF][boff[ni]]);                      \
      _Pragma("unroll")                                                        \
      for (int mi = 0; mi < 4; ++mi) {                                         \
        accv[mi][ni] = __builtin_amdgcn_mfma_f32_16x16x32_bf16(av[mi], b8v, accv[mi][ni], 0, 0, 0); \
        accg[mi][ni] = __builtin_amdgcn_mfma_f32_16x16x32_bf16(av[mi], b8g, accg[mi][ni], 0, 0, 0); \
      }                                                                        \
    }                                                                          \
  }

  // prologue: stage k-tile 0 into buf0
  G1_STAGE(0);
  __syncthreads();
  for (int kt = 0; kt < E_DIM / 32 - 2; kt += 2) {
    G1_STAGE(1);      // k-tile kt+1
    G1_COMPUTE(0);    // k-tile kt
    __syncthreads();
    G1_STAGE(0);      // k-tile kt+2
    G1_COMPUTE(1);    // k-tile kt+1
    __syncthreads();
  }
  // tail: k-tiles NK-2, NK-1
  G1_STAGE(1);
  G1_COMPUTE(0);
  __syncthreads();
  G1_COMPUTE(1);

  // epilogue: silu(hv) * hg -> h (bf16)
  float bvv[4], bgv[4];
#pragma unroll
  for (int ni = 0; ni < 4; ++ni) {
    int n = n0 + wn * 64 + ni * 16 + r;
    bvv[ni] = (n < HDIM) ? bv[e * HDIM + n] : 0.f;
    bgv[ni] = (n < HDIM) ? bg[e * HDIM + n] : 0.f;
  }
#pragma unroll
  for (int mi = 0; mi < 4; ++mi) {
#pragma unroll
    for (int rr = 0; rr < 4; ++rr) {
      int m_loc = wm * 64 + mi * 16 + q * 4 + rr;
      int m = m0 + m_loc;
      if (m >= Me) continue;
      size_t hrow = (size_t)(off + m) * HP;
#pragma unroll
      for (int ni = 0; ni < 4; ++ni) {
        int n = n0 + wn * 64 + ni * 16 + r;
        float hv = accv[mi][ni][rr] + bvv[ni];
        float hg = accg[mi][ni][rr] + bgv[ni];
        float sgm = 1.f / (1.f + __expf(-hv));
        h[hrow + n] = f2bf(hv * sgm * hg);
      }
    }
  }
}

// ---------------- GEMM2: pair_out = h @ Wo + bo ----------------
// 128m x 128n block, BK=32, same 2-phase double-buffered scheme.
__global__ __launch_bounds__(256, 2) void gemm2_k(
    const __hip_bfloat16* __restrict__ hb,
    const int* __restrict__ counts, const int* __restrict__ offsets,
    const int* __restrict__ slot_e, const int* __restrict__ slot_m0,
    const float* __restrict__ bo,
    const __hip_bfloat16* __restrict__ WoT,
    float* __restrict__ pout) {
  int slot = blockIdx.y;
  int e = slot_e[slot];
  if (e < 0) return;
  int m0 = slot_m0[slot];
  int Me = counts[e], off = offsets[e];
  int n0 = blockIdx.x * 128;

  __shared__ __align__(16) __hip_bfloat16 sA[2][128 * 32];
  __shared__ __align__(16) __hip_bfloat16 sB[2][128 * 32];

  int tid = threadIdx.x;
  int wid = tid >> 6, lane = tid & 63;
  int wm = wid >> 1, wn = wid & 1;
  int q = lane >> 4, r = lane & 15;

  int csw = (q ^ (r & 3)) << 3;
  int aoff[4], boff[4];
#pragma unroll
  for (int mi = 0; mi < 4; ++mi) aoff[mi] = (wm * 64 + mi * 16 + r) * 32 + csw;
#pragma unroll
  for (int ni = 0; ni < 4; ++ni) boff[ni] = (wn * 64 + ni * 16 + r) * 32 + csw;

  int srow4   = lane >> 2;
  int schunk4 = (lane & 3) ^ (srow4 & 3);
  const __hip_bfloat16* gA = hb + (size_t)(off + m0 + wid * 16 + srow4) * HP + schunk4 * 8;
  const __hip_bfloat16* gB = WoT + (size_t)e * ((size_t)E_DIM * HP) +
                             (size_t)(n0 + wid * 16 + srow4) * HP + schunk4 * 8;

  floatx4 acc[4][4];
  floatx4 zz = {0.f, 0.f, 0.f, 0.f};
#pragma unroll
  for (int mi = 0; mi < 4; ++mi)
#pragma unroll
    for (int ni = 0; ni < 4; ++ni) acc[mi][ni] = zz;

#define G2_STAGE(BUF)                                                          \
  {                                                                            \
    _Pragma("unroll")                                                          \
    for (int i = 0; i < 2; ++i) {                                              \
      gload16(gA + (size_t)i * 64 * HP, &sA[BUF][(wid + i * 4) * 512]);        \
      gload16(gB + (size_t)i * 64 * HP, &sB[BUF][(wid + i * 4) * 512]);        \
    }                                                                          \
    gA += 32; gB += 32;                                                        \
  }

#define G2_COMPUTE(BUF)                                                        \
  {                                                                            \
    short8 av[4];                                                              \
    _Pragma("unroll")                                                          \
    for (int mi = 0; mi < 4; ++mi)                                             \
      av[mi] = *(const short8*)(&sA[BUF][aoff[mi]]);                           \
    _Pragma("unroll")                                                          \
    for (int ni = 0; ni < 4; ++ni) {                                           \
      short8 b8 = *(const short8*)(&sB[BUF][boff[ni]]);                        \
      _Pragma("unroll")                                                        \
      for (int mi = 0; mi < 4; ++mi)                                           \
        acc[mi][ni] = __builtin_amdgcn_mfma_f32_16x16x32_bf16(av[mi], b8, acc[mi][ni], 0, 0, 0); \
    }                                                                          \
  }

  G2_STAGE(0);
  __syncthreads();
  for (int kt = 0; kt < HP / 32 - 2; kt += 2) {
    G2_STAGE(1);
    G2_COMPUTE(0);
    __syncthreads();
    G2_STAGE(0);
    G2_COMPUTE(1);
    __syncthreads();
  }
  G2_STAGE(1);
  G2_COMPUTE(0);
  __syncthreads();
  G2_COMPUTE(1);

#pragma unroll
  for (int mi = 0; mi < 4; ++mi) {
#pragma unroll
    for (int rr = 0; rr < 4; ++rr) {
      int m_loc = wm * 64 + mi * 16 + q * 4 + rr;
      int m = m0 + m_loc;
      if (m >= Me) continue;
      size_t orow = (size_t)(off + m) * E_DIM;
#pragma unroll
      for (int ni = 0; ni < 4; ++ni) {
        int n = n0 + wn * 64 + ni * 16 + r;
        pout[orow + n] = acc[mi][ni][rr] + bo[e * E_DIM + n];
      }
    }
  }
}

// ---------------- combine + residual + LayerNorm ----------------
__global__ __launch_bounds__(256) void ln_k(const float* __restrict__ x,
    const float* __restrict__ pout, const int* __restrict__ pair_pos,
    const float* __restrict__ pair_w, const float* __restrict__ ln_g,
    const float* __restrict__ ln_b, float* __restrict__ out) {
  int t = blockIdx.x, tid = threadIdx.x;
  int p0 = pair_pos[2 * t], p1 = pair_pos[2 * t + 1];
  float w0 = pair_w[p0], w1 = pair_w[p1];
  const float* xr = x + (size_t)t * E_DIM;
  const float* r0 = pout + (size_t)p0 * E_DIM;
  const float* r1 = pout + (size_t)p1 * E_DIM;
  float y[4];
  float s = 0.f, ss = 0.f;
#pragma unroll
  for (int i = 0; i < 4; ++i) {
    int e = tid + 256 * i;
    y[i] = xr[e] + w0 * r0[e] + w1 * r1[e];
    s += y[i];
    ss += y[i] * y[i];
  }
#pragma unroll
  for (int o = 32; o; o >>= 1) { s += __shfl_xor(s, o, 64); ss += __shfl_xor(ss, o, 64); }
  __shared__ float red[8];
  int wid = tid >> 6, lane = tid & 63;
  if (lane == 0) { red[wid] = s; red[4 + wid] = ss; }
  __syncthreads();
  s  = red[0] + red[1] + red[2] + red[3];
  ss = red[4] + red[5] + red[6] + red[7];
  float mu = s * (1.f / E_DIM);
  float var = ss * (1.f / E_DIM) - mu * mu;
  float rs = rsqrtf(var + LN_EPS);
#pragma unroll
  for (int i = 0; i < 4; ++i) {
    int e = tid + 256 * i;
    out[(size_t)t * E_DIM + e] = ln_g[e] * (y[i] - mu) * rs + ln_b[e];
  }
}

extern "C" void kernel_launch(void* const* d_in, const int* in_sizes, int n_in,
                              void* d_out, int out_size, void* d_ws, size_t ws_size,
                              hipStream_t stream) {
  const float* x    = (const float*)d_in[0];
  const float* Wr   = (const float*)d_in[1];
  const float* Wv   = (const float*)d_in[2];
  const float* bv   = (const float*)d_in[3];
  const float* Wg   = (const float*)d_in[4];
  const float* bg   = (const float*)d_in[5];
  const float* Wo   = (const float*)d_in[6];
  const float* bo   = (const float*)d_in[7];
  const float* ln_g = (const float*)d_in[8];
  const float* ln_b = (const float*)d_in[9];
  float* out = (float*)d_out;

  char* ws = (char*)d_ws;
  size_t off = 0;
  auto alloc = [&](size_t bytes) -> void* {
    void* p = ws + off;
    off = (off + bytes + 255) & ~(size_t)255;
    return p;
  };
  int*   counts     = (int*)alloc(32);
  int*   cursor     = (int*)alloc(32);
  int*   offsets    = (int*)alloc(32);
  int*   slot_e     = (int*)alloc(NSLOT * 4);
  int*   slot_m0    = (int*)alloc(NSLOT * 4);
  int*   tk_idx     = (int*)alloc((size_t)NTOK * 2 * 4);
  float* tk_w       = (float*)alloc((size_t)NTOK * 2 * 4);
  int*   pair_token = (int*)alloc((size_t)NPAIR * 4);
  float* pair_w     = (float*)alloc((size_t)NPAIR * 4);
  int*   pair_pos   = (int*)alloc((size_t)NPAIR * 4);
  __hip_bfloat16* xs   = (__hip_bfloat16*)alloc((size_t)(NPAIR + 128) * E_DIM * 2);
  __hip_bfloat16* hbuf = (__hip_bfloat16*)alloc((size_t)(NPAIR + 128) * HP * 2);
  float* pout = (float*)alloc((size_t)NPAIR * E_DIM * 4);

  size_t welems = (size_t)NEXP * HP * E_DIM;
  __hip_bfloat16* WvT = (__hip_bfloat16*)alloc(welems * 2);
  __hip_bfloat16* WgT = (__hip_bfloat16*)alloc(welems * 2);
  __hip_bfloat16* WoT = (__hip_bfloat16*)alloc(welems * 2);

  hipMemsetAsync(d_ws, 0, 1024, stream);  // counts / cursor / offsets / slots

  router_k<<<NTOK / 4, 256, 0, stream>>>(x, Wr, counts, tk_idx, tk_w);
  offsets_k<<<1, 64, 0, stream>>>(counts, offsets, cursor, slot_e, slot_m0);
  scatter_k<<<NTOK / 256, 256, 0, stream>>>(tk_idx, tk_w, cursor, pair_token, pair_w, pair_pos);
  gatherx_k<<<NPAIR, 256, 0, stream>>>(x, pair_token, xs);

  tcvt_k<<<dim3(HP / 64, E_DIM / 64, NEXP), 256, 0, stream>>>(
      Wv, WvT, E_DIM, HDIM, E_DIM, (size_t)E_DIM * HDIM, (size_t)HP * E_DIM);
  tcvt_k<<<dim3(HP / 64, E_DIM / 64, NEXP), 256, 0, stream>>>(
      Wg, WgT, E_DIM, HDIM, E_DIM, (size_t)E_DIM * HDIM, (size_t)HP * E_DIM);
  tcvt_k<<<dim3(E_DIM / 64, HP / 64, NEXP), 256, 0, stream>>>(
      Wo, WoT, HDIM, E_DIM, HP, (size_t)HDIM * E_DIM, (size_t)E_DIM * HP);

  gemm1_k<<<dim3(HP / 128, NSLOT), 256, 0, stream>>>(
      xs, counts, offsets, slot_e, slot_m0, bv, bg, WvT, WgT, hbuf);
  gemm2_k<<<dim3(E_DIM / 128, NSLOT), 256, 0, stream>>>(
      hbuf, counts, offsets, slot_e, slot_m0, bo, WoT, pout);

  ln_k<<<NTOK, 256, 0, stream>>>(x, pout, pair_pos, pair_w, ln_g, ln_b, out);
}

// Round 4
// 729.846 us; speedup vs baseline: 1.0029x; 1.0029x over previous
//
#include <hip/hip_runtime.h>
#include <hip/hip_bf16.h>

#define E_DIM 1024
#define HDIM  2730
#define HP    2816   // H padded to multiple of 128
#define NEXP  8
#define NTOK  4096
#define NPAIR 8192
#define NSLOT 72     // max m-tiles of 128 over all experts (<=71) + pad
#define LN_EPS 1e-5f

typedef __attribute__((ext_vector_type(8))) short  short8;
typedef __attribute__((ext_vector_type(4))) short  short4v;
typedef __attribute__((ext_vector_type(4))) float  floatx4;
typedef __attribute__((ext_vector_type(4))) int    intx4;

__device__ __forceinline__ __hip_bfloat16 f2bf(float f) { return __float2bfloat16(f); }

// async global->LDS, 16B per lane; LDS dest = wave-uniform base + lane*16
__device__ __forceinline__ void gload16(const __hip_bfloat16* g, __hip_bfloat16* l) {
  __builtin_amdgcn_global_load_lds(
      (const __attribute__((address_space(1))) void*)(g),
      (__attribute__((address_space(3))) void*)(l), 16, 0, 0);
}

// ---------------- router: fp32 logits, top-2, softmax weights ----------------
__global__ __launch_bounds__(256) void router_k(const float* __restrict__ x,
    const float* __restrict__ Wr, int* __restrict__ counts,
    int* __restrict__ tk_idx, float* __restrict__ tk_w) {
  int wid = threadIdx.x >> 6, lane = threadIdx.x & 63;
  int t = blockIdx.x * 4 + wid;
  const float* xr = x + (size_t)t * E_DIM;
  float xv[16];
#pragma unroll
  for (int i = 0; i < 16; ++i) xv[i] = xr[lane + 64 * i];
  float lg[8];
#pragma unroll
  for (int e = 0; e < 8; ++e) {
    const float* wr = Wr + e * E_DIM;
    float a = 0.f;
#pragma unroll
    for (int i = 0; i < 16; ++i) a += xv[i] * wr[lane + 64 * i];
#pragma unroll
    for (int o = 32; o; o >>= 1) a += __shfl_xor(a, o, 64);
    lg[e] = a;
  }
  if (lane == 0) {
    int i0 = 0; float l0 = lg[0];
#pragma unroll
    for (int e = 1; e < 8; ++e) if (lg[e] > l0) { l0 = lg[e]; i0 = e; }
    int i1 = -1; float l1 = -1e30f;
#pragma unroll
    for (int e = 0; e < 8; ++e) if (e != i0 && lg[e] > l1) { l1 = lg[e]; i1 = e; }
    float w0 = 1.f / (1.f + __expf(l1 - l0));
    atomicAdd(&counts[i0], 1);
    atomicAdd(&counts[i1], 1);
    tk_idx[2 * t]     = i0;  tk_idx[2 * t + 1] = i1;
    tk_w[2 * t]       = w0;  tk_w[2 * t + 1]   = 1.f - w0;
  }
}

// offsets + compact (expert, m0) tile table: active slots contiguous from 0.
__global__ void offsets_k(const int* __restrict__ counts, int* __restrict__ offsets,
                          int* __restrict__ cursor,
                          int* __restrict__ slot_e, int* __restrict__ slot_m0) {
  if (threadIdx.x == 0) {
    int off = 0, s = 0;
    for (int e = 0; e < NEXP; ++e) {
      offsets[e] = off; cursor[e] = off;
      for (int m0 = 0; m0 < counts[e]; m0 += 128) { slot_e[s] = e; slot_m0[s] = m0; ++s; }
      off += counts[e];
    }
    for (; s < NSLOT; ++s) { slot_e[s] = -1; slot_m0[s] = 0; }
  }
}

__global__ __launch_bounds__(256) void scatter_k(const int* __restrict__ tk_idx,
    const float* __restrict__ tk_w, int* __restrict__ cursor,
    int* __restrict__ pair_token, float* __restrict__ pair_w, int* __restrict__ pair_pos) {
  int t = blockIdx.x * 256 + threadIdx.x;
#pragma unroll
  for (int k = 0; k < 2; ++k) {
    int e = tk_idx[2 * t + k];
    int pos = atomicAdd(&cursor[e], 1);
    pair_token[pos] = t;
    pair_w[pos] = tk_w[2 * t + k];
    pair_pos[2 * t + k] = pos;
  }
}

// ---------------- expert-sorted token rows: xs[p] = bf16(x[pair_token[p]]) ----------------
__global__ __launch_bounds__(256) void gatherx_k(const float* __restrict__ x,
    const int* __restrict__ pair_token, __hip_bfloat16* __restrict__ xs) {
  int p = blockIdx.x;
  int t = pair_token[p];
  const float* src = x + (size_t)t * E_DIM;
  __hip_bfloat16* dst = xs + (size_t)p * E_DIM;
  int i = threadIdx.x * 4;
  floatx4 v = *(const floatx4*)(src + i);
  union { __hip_bfloat16 h[4]; short4v s; } u;
#pragma unroll
  for (int j = 0; j < 4; ++j) u.h[j] = f2bf(v[j]);
  *(short4v*)(dst + i) = u.s;
}

// ------------- transpose + convert: in fp32 [R][C] -> out bf16 [Cp][outRS] -------------
__global__ __launch_bounds__(256) void tcvt_k(const float* __restrict__ in,
    __hip_bfloat16* __restrict__ out, int R, int C, int outRS,
    size_t inExpStride, size_t outExpStride) {
  __shared__ float tile[64 * 65];
  int e = blockIdx.z;
  const float* ip = in + inExpStride * e;
  __hip_bfloat16* op = out + outExpStride * e;
  int c0 = blockIdx.x * 64, r0 = blockIdx.y * 64;
#pragma unroll
  for (int i = 0; i < 16; ++i) {
    int idx = i * 256 + threadIdx.x;
    int rr = idx >> 6, cc = idx & 63;
    int gr = r0 + rr, gc = c0 + cc;
    tile[rr * 65 + cc] = (gr < R && gc < C) ? ip[(size_t)gr * C + gc] : 0.f;
  }
  __syncthreads();
#pragma unroll
  for (int i = 0; i < 2; ++i) {
    int idx = i * 256 + threadIdx.x;
    int cc = idx >> 3, rb = (idx & 7) * 8;
    union { __hip_bfloat16 h[8]; intx4 v; } u;
#pragma unroll
    for (int j = 0; j < 8; ++j) u.h[j] = f2bf(tile[(rb + j) * 65 + cc]);
    *(intx4*)(op + (size_t)(c0 + cc) * outRS + (r0 + rb)) = u.v;
  }
}

// ---------------- GEMM1: h = silu(xs@Wv+bv) * (xs@Wg+bg) ----------------
// 128m x 128n block (dual B), BK=32, 2-phase double-buffered LDS.
// Swizzle key is (row>>1)&3 (NOT row&3): with 64B rows, bank-group =
// (r&1, chunk); keying on (r>>1)&3 makes each 16-lane read phase cover all
// 8 four-bank groups -> conflict-free (R3's row&3 key hit only 4 -> 9M confl).
__global__ __launch_bounds__(256, 2) void gemm1_k(
    const __hip_bfloat16* __restrict__ xs,
    const int* __restrict__ counts, const int* __restrict__ offsets,
    const int* __restrict__ slot_e, const int* __restrict__ slot_m0,
    const float* __restrict__ bv, const float* __restrict__ bg,
    const __hip_bfloat16* __restrict__ WvT, const __hip_bfloat16* __restrict__ WgT,
    __hip_bfloat16* __restrict__ h) {
  int slot = blockIdx.y;
  int e = slot_e[slot];
  if (e < 0) return;
  int m0 = slot_m0[slot];
  int Me = counts[e], off = offsets[e];
  int n0 = blockIdx.x * 128;

  __shared__ __align__(16) __hip_bfloat16 sA[2][128 * 32];
  __shared__ __align__(16) __hip_bfloat16 sBv[2][128 * 32];
  __shared__ __align__(16) __hip_bfloat16 sBg[2][128 * 32];

  int tid = threadIdx.x;
  int wid = tid >> 6, lane = tid & 63;
  int wm = wid >> 1, wn = wid & 1;
  int q = lane >> 4, r = lane & 15;

  // fragment read offsets (halfs): row*32 + ((q ^ ((row>>1)&3))<<3);
  // (row>>1)&3 == (r>>1)&3 since all row bases are multiples of 16.
  int csw = (q ^ ((r >> 1) & 3)) << 3;
  int aoff[4], boff[4];
#pragma unroll
  for (int mi = 0; mi < 4; ++mi) aoff[mi] = (wm * 64 + mi * 16 + r) * 32 + csw;
#pragma unroll
  for (int ni = 0; ni < 4; ++ni) boff[ni] = (wn * 64 + ni * 16 + r) * 32 + csw;

  // staging: each gload16 covers 16 rows x 64B. lane l -> row l>>2, lds chunk
  // l&3; source chunk = (l&3) ^ ((l>>3)&3)  [matches read key (row>>1)&3].
  int srow4   = lane >> 2;
  int schunk4 = (lane & 3) ^ ((lane >> 3) & 3);
  const __hip_bfloat16* gA = xs + (size_t)(off + m0 + wid * 16 + srow4) * E_DIM + schunk4 * 8;
  size_t wb = (size_t)e * ((size_t)HP * E_DIM);
  size_t browoff = wb + (size_t)(n0 + wid * 16 + srow4) * E_DIM + schunk4 * 8;
  const __hip_bfloat16* gv = WvT + browoff;
  const __hip_bfloat16* gg = WgT + browoff;

  floatx4 accv[4][4], accg[4][4];
  floatx4 zz = {0.f, 0.f, 0.f, 0.f};
#pragma unroll
  for (int mi = 0; mi < 4; ++mi)
#pragma unroll
    for (int ni = 0; ni < 4; ++ni) { accv[mi][ni] = zz; accg[mi][ni] = zz; }

#define G1_STAGE(BUF)                                                          \
  {                                                                            \
    _Pragma("unroll")                                                          \
    for (int i = 0; i < 2; ++i) {                                              \
      gload16(gA + (size_t)i * 64 * E_DIM, &sA[BUF][(wid + i * 4) * 512]);     \
      gload16(gv + (size_t)i * 64 * E_DIM, &sBv[BUF][(wid + i * 4) * 512]);    \
      gload16(gg + (size_t)i * 64 * E_DIM, &sBg[BUF][(wid + i * 4) * 512]);    \
    }                                                                          \
    gA += 32; gv += 32; gg += 32;                                              \
  }

#define G1_COMPUTE(BUF)                                                        \
  {                                                                            \
    short8 av[4];                                                              \
    _Pragma("unroll")                                                          \
    for (int mi = 0; mi < 4; ++mi)                                             \
      av[mi] = *(const short8*)(&sA[BUF][aoff[mi]]);                           \
    _Pragma("unroll")                                                          \
    for (int ni = 0; ni < 4; ++ni) {                                           \
      short8 b8v = *(const short8*)(&sBv[BUF][boff[ni]]);                      \
      short8 b8g = *(const short8*)(&sBg[BUF][boff[ni]]);                      \
      _Pragma("unroll")                                                        \
      for (int mi = 0; mi < 4; ++mi) {                                         \
        accv[mi][ni] = __builtin_amdgcn_mfma_f32_16x16x32_bf16(av[mi], b8v, accv[mi][ni], 0, 0, 0); \
        accg[mi][ni] = __builtin_amdgcn_mfma_f32_16x16x32_bf16(av[mi], b8g, accg[mi][ni], 0, 0, 0); \
      }                                                                        \
    }                                                                          \
  }

  // prologue: stage k-tile 0 into buf0
  G1_STAGE(0);
  __syncthreads();
  for (int kt = 0; kt < E_DIM / 32 - 2; kt += 2) {
    G1_STAGE(1);      // k-tile kt+1
    G1_COMPUTE(0);    // k-tile kt
    __syncthreads();
    G1_STAGE(0);      // k-tile kt+2
    G1_COMPUTE(1);    // k-tile kt+1
    __syncthreads();
  }
  // tail: k-tiles NK-2, NK-1
  G1_STAGE(1);
  G1_COMPUTE(0);
  __syncthreads();
  G1_COMPUTE(1);

  // epilogue: silu(hv) * hg -> h (bf16)
  float bvv[4], bgv[4];
#pragma unroll
  for (int ni = 0; ni < 4; ++ni) {
    int n = n0 + wn * 64 + ni * 16 + r;
    bvv[ni] = (n < HDIM) ? bv[e * HDIM + n] : 0.f;
    bgv[ni] = (n < HDIM) ? bg[e * HDIM + n] : 0.f;
  }
#pragma unroll
  for (int mi = 0; mi < 4; ++mi) {
#pragma unroll
    for (int rr = 0; rr < 4; ++rr) {
      int m_loc = wm * 64 + mi * 16 + q * 4 + rr;
      int m = m0 + m_loc;
      if (m >= Me) continue;
      size_t hrow = (size_t)(off + m) * HP;
#pragma unroll
      for (int ni = 0; ni < 4; ++ni) {
        int n = n0 + wn * 64 + ni * 16 + r;
        float hv = accv[mi][ni][rr] + bvv[ni];
        float hg = accg[mi][ni][rr] + bgv[ni];
        float sgm = 1.f / (1.f + __expf(-hv));
        h[hrow + n] = f2bf(hv * sgm * hg);
      }
    }
  }
}

// ---------------- GEMM2: pair_out = h @ Wo + bo ----------------
// 128m x 128n block, BK=32, same 2-phase scheme + corrected swizzle key.
__global__ __launch_bounds__(256, 2) void gemm2_k(
    const __hip_bfloat16* __restrict__ hb,
    const int* __restrict__ counts, const int* __restrict__ offsets,
    const int* __restrict__ slot_e, const int* __restrict__ slot_m0,
    const float* __restrict__ bo,
    const __hip_bfloat16* __restrict__ WoT,
    float* __restrict__ pout) {
  int slot = blockIdx.y;
  int e = slot_e[slot];
  if (e < 0) return;
  int m0 = slot_m0[slot];
  int Me = counts[e], off = offsets[e];
  int n0 = blockIdx.x * 128;

  __shared__ __align__(16) __hip_bfloat16 sA[2][128 * 32];
  __shared__ __align__(16) __hip_bfloat16 sB[2][128 * 32];

  int tid = threadIdx.x;
  int wid = tid >> 6, lane = tid & 63;
  int wm = wid >> 1, wn = wid & 1;
  int q = lane >> 4, r = lane & 15;

  int csw = (q ^ ((r >> 1) & 3)) << 3;
  int aoff[4], boff[4];
#pragma unroll
  for (int mi = 0; mi < 4; ++mi) aoff[mi] = (wm * 64 + mi * 16 + r) * 32 + csw;
#pragma unroll
  for (int ni = 0; ni < 4; ++ni) boff[ni] = (wn * 64 + ni * 16 + r) * 32 + csw;

  int srow4   = lane >> 2;
  int schunk4 = (lane & 3) ^ ((lane >> 3) & 3);
  const __hip_bfloat16* gA = hb + (size_t)(off + m0 + wid * 16 + srow4) * HP + schunk4 * 8;
  const __hip_bfloat16* gB = WoT + (size_t)e * ((size_t)E_DIM * HP) +
                             (size_t)(n0 + wid * 16 + srow4) * HP + schunk4 * 8;

  floatx4 acc[4][4];
  floatx4 zz = {0.f, 0.f, 0.f, 0.f};
#pragma unroll
  for (int mi = 0; mi < 4; ++mi)
#pragma unroll
    for (int ni = 0; ni < 4; ++ni) acc[mi][ni] = zz;

#define G2_STAGE(BUF)                                                          \
  {                                                                            \
    _Pragma("unroll")                                                          \
    for (int i = 0; i < 2; ++i) {                                              \
      gload16(gA + (size_t)i * 64 * HP, &sA[BUF][(wid + i * 4) * 512]);        \
      gload16(gB + (size_t)i * 64 * HP, &sB[BUF][(wid + i * 4) * 512]);        \
    }                                                                          \
    gA += 32; gB += 32;                                                        \
  }

#define G2_COMPUTE(BUF)                                                        \
  {                                                                            \
    short8 av[4];                                                              \
    _Pragma("unroll")                                                          \
    for (int mi = 0; mi < 4; ++mi)                                             \
      av[mi] = *(const short8*)(&sA[BUF][aoff[mi]]);                           \
    _Pragma("unroll")                                                          \
    for (int ni = 0; ni < 4; ++ni) {                                           \
      short8 b8 = *(const short8*)(&sB[BUF][boff[ni]]);                        \
      _Pragma("unroll")                                                        \
      for (int mi = 0; mi < 4; ++mi)                                           \
        acc[mi][ni] = __builtin_amdgcn_mfma_f32_16x16x32_bf16(av[mi], b8, acc[mi][ni], 0, 0, 0); \
    }                                                                          \
  }

  G2_STAGE(0);
  __syncthreads();
  for (int kt = 0; kt < HP / 32 - 2; kt += 2) {
    G2_STAGE(1);
    G2_COMPUTE(0);
    __syncthreads();
    G2_STAGE(0);
    G2_COMPUTE(1);
    __syncthreads();
  }
  G2_STAGE(1);
  G2_COMPUTE(0);
  __syncthreads();
  G2_COMPUTE(1);

#pragma unroll
  for (int mi = 0; mi < 4; ++mi) {
#pragma unroll
    for (int rr = 0; rr < 4; ++rr) {
      int m_loc = wm * 64 + mi * 16 + q * 4 + rr;
      int m = m0 + m_loc;
      if (m >= Me) continue;
      size_t orow = (size_t)(off + m) * E_DIM;
#pragma unroll
      for (int ni = 0; ni < 4; ++ni) {
        int n = n0 + wn * 64 + ni * 16 + r;
        pout[orow + n] = acc[mi][ni][rr] + bo[e * E_DIM + n];
      }
    }
  }
}

// ---------------- combine + residual + LayerNorm ----------------
__global__ __launch_bounds__(256) void ln_k(const float* __restrict__ x,
    const float* __restrict__ pout, const int* __restrict__ pair_pos,
    const float* __restrict__ pair_w, const float* __restrict__ ln_g,
    const float* __restrict__ ln_b, float* __restrict__ out) {
  int t = blockIdx.x, tid = threadIdx.x;
  int p0 = pair_pos[2 * t], p1 = pair_pos[2 * t + 1];
  float w0 = pair_w[p0], w1 = pair_w[p1];
  const float* xr = x + (size_t)t * E_DIM;
  const float* r0 = pout + (size_t)p0 * E_DIM;
  const float* r1 = pout + (size_t)p1 * E_DIM;
  float y[4];
  float s = 0.f, ss = 0.f;
#pragma unroll
  for (int i = 0; i < 4; ++i) {
    int e = tid + 256 * i;
    y[i] = xr[e] + w0 * r0[e] + w1 * r1[e];
    s += y[i];
    ss += y[i] * y[i];
  }
#pragma unroll
  for (int o = 32; o; o >>= 1) { s += __shfl_xor(s, o, 64); ss += __shfl_xor(ss, o, 64); }
  __shared__ float red[8];
  int wid = tid >> 6, lane = tid & 63;
  if (lane == 0) { red[wid] = s; red[4 + wid] = ss; }
  __syncthreads();
  s  = red[0] + red[1] + red[2] + red[3];
  ss = red[4] + red[5] + red[6] + red[7];
  float mu = s * (1.f / E_DIM);
  float var = ss * (1.f / E_DIM) - mu * mu;
  float rs = rsqrtf(var + LN_EPS);
#pragma unroll
  for (int i = 0; i < 4; ++i) {
    int e = tid + 256 * i;
    out[(size_t)t * E_DIM + e] = ln_g[e] * (y[i] - mu) * rs + ln_b[e];
  }
}

extern "C" void kernel_launch(void* const* d_in, const int* in_sizes, int n_in,
                              void* d_out, int out_size, void* d_ws, size_t ws_size,
                              hipStream_t stream) {
  const float* x    = (const float*)d_in[0];
  const float* Wr   = (const float*)d_in[1];
  const float* Wv   = (const float*)d_in[2];
  const float* bv   = (const float*)d_in[3];
  const float* Wg   = (const float*)d_in[4];
  const float* bg   = (const float*)d_in[5];
  const float* Wo   = (const float*)d_in[6];
  const float* bo   = (const float*)d_in[7];
  const float* ln_g = (const float*)d_in[8];
  const float* ln_b = (const float*)d_in[9];
  float* out = (float*)d_out;

  char* ws = (char*)d_ws;
  size_t off = 0;
  auto alloc = [&](size_t bytes) -> void* {
    void* p = ws + off;
    off = (off + bytes + 255) & ~(size_t)255;
    return p;
  };
  int*   counts     = (int*)alloc(32);
  int*   cursor     = (int*)alloc(32);
  int*   offsets    = (int*)alloc(32);
  int*   slot_e     = (int*)alloc(NSLOT * 4);
  int*   slot_m0    = (int*)alloc(NSLOT * 4);
  int*   tk_idx     = (int*)alloc((size_t)NTOK * 2 * 4);
  float* tk_w       = (float*)alloc((size_t)NTOK * 2 * 4);
  int*   pair_token = (int*)alloc((size_t)NPAIR * 4);
  float* pair_w     = (float*)alloc((size_t)NPAIR * 4);
  int*   pair_pos   = (int*)alloc((size_t)NPAIR * 4);
  __hip_bfloat16* xs   = (__hip_bfloat16*)alloc((size_t)(NPAIR + 128) * E_DIM * 2);
  __hip_bfloat16* hbuf = (__hip_bfloat16*)alloc((size_t)(NPAIR + 128) * HP * 2);
  float* pout = (float*)alloc((size_t)NPAIR * E_DIM * 4);

  size_t welems = (size_t)NEXP * HP * E_DIM;
  __hip_bfloat16* WvT = (__hip_bfloat16*)alloc(welems * 2);
  __hip_bfloat16* WgT = (__hip_bfloat16*)alloc(welems * 2);
  __hip_bfloat16* WoT = (__hip_bfloat16*)alloc(welems * 2);

  hipMemsetAsync(d_ws, 0, 1024, stream);  // counts / cursor / offsets / slots

  router_k<<<NTOK / 4, 256, 0, stream>>>(x, Wr, counts, tk_idx, tk_w);
  offsets_k<<<1, 64, 0, stream>>>(counts, offsets, cursor, slot_e, slot_m0);
  scatter_k<<<NTOK / 256, 256, 0, stream>>>(tk_idx, tk_w, cursor, pair_token, pair_w, pair_pos);
  gatherx_k<<<NPAIR, 256, 0, stream>>>(x, pair_token, xs);

  tcvt_k<<<dim3(HP / 64, E_DIM / 64, NEXP), 256, 0, stream>>>(
      Wv, WvT, E_DIM, HDIM, E_DIM, (size_t)E_DIM * HDIM, (size_t)HP * E_DIM);
  tcvt_k<<<dim3(HP / 64, E_DIM / 64, NEXP), 256, 0, stream>>>(
      Wg, WgT, E_DIM, HDIM, E_DIM, (size_t)E_DIM * HDIM, (size_t)HP * E_DIM);
  tcvt_k<<<dim3(E_DIM / 64, HP / 64, NEXP), 256, 0, stream>>>(
      Wo, WoT, HDIM, E_DIM, HP, (size_t)HDIM * E_DIM, (size_t)E_DIM * HP);

  gemm1_k<<<dim3(HP / 128, NSLOT), 256, 0, stream>>>(
      xs, counts, offsets, slot_e, slot_m0, bv, bg, WvT, WgT, hbuf);
  gemm2_k<<<dim3(E_DIM / 128, NSLOT), 256, 0, stream>>>(
      hbuf, counts, offsets, slot_e, slot_m0, bo, WoT, pout);

  ln_k<<<NTOK, 256, 0, stream>>>(x, pout, pair_pos, pair_w, ln_g, ln_b, out);
}

// Round 5
// 711.119 us; speedup vs baseline: 1.0293x; 1.0263x over previous
//
#include <hip/hip_runtime.h>
#include <hip/hip_bf16.h>

#define E_DIM 1024
#define HDIM  2730
#define HP    2816   // H padded to multiple of 128
#define NEXP  8
#define NTOK  4096
#define NPAIR 8192
#define NSLOT 72     // max m-tiles of 128 over all experts (<=71) + pad
#define LN_EPS 1e-5f
#define BUFH  (128 * 32)   // halfs per matrix per k-tile buffer

typedef __attribute__((ext_vector_type(8))) short  short8;
typedef __attribute__((ext_vector_type(4))) short  short4v;
typedef __attribute__((ext_vector_type(4))) float  floatx4;
typedef __attribute__((ext_vector_type(4))) int    intx4;

__device__ __forceinline__ __hip_bfloat16 f2bf(float f) { return __float2bfloat16(f); }

// async global->LDS, 16B per lane; LDS dest = wave-uniform base + lane*16
__device__ __forceinline__ void gload16(const __hip_bfloat16* g, __hip_bfloat16* l) {
  __builtin_amdgcn_global_load_lds(
      (const __attribute__((address_space(1))) void*)(g),
      (__attribute__((address_space(3))) void*)(l), 16, 0, 0);
}

// counted vmem waits (T4): never drain to 0 in the main loop.
#define VMC6 do { asm volatile("s_waitcnt vmcnt(6)" ::: "memory"); __builtin_amdgcn_sched_barrier(0); } while (0)
#define VMC4 do { asm volatile("s_waitcnt vmcnt(4)" ::: "memory"); __builtin_amdgcn_sched_barrier(0); } while (0)
#define VMC0 do { asm volatile("s_waitcnt vmcnt(0)" ::: "memory"); __builtin_amdgcn_sched_barrier(0); } while (0)
#define BAR  __builtin_amdgcn_s_barrier()

// ---------------- router: fp32 logits, top-2, softmax weights ----------------
__global__ __launch_bounds__(256) void router_k(const float* __restrict__ x,
    const float* __restrict__ Wr, int* __restrict__ counts,
    int* __restrict__ tk_idx, float* __restrict__ tk_w) {
  int wid = threadIdx.x >> 6, lane = threadIdx.x & 63;
  int t = blockIdx.x * 4 + wid;
  const float* xr = x + (size_t)t * E_DIM;
  float xv[16];
#pragma unroll
  for (int i = 0; i < 16; ++i) xv[i] = xr[lane + 64 * i];
  float lg[8];
#pragma unroll
  for (int e = 0; e < 8; ++e) {
    const float* wr = Wr + e * E_DIM;
    float a = 0.f;
#pragma unroll
    for (int i = 0; i < 16; ++i) a += xv[i] * wr[lane + 64 * i];
#pragma unroll
    for (int o = 32; o; o >>= 1) a += __shfl_xor(a, o, 64);
    lg[e] = a;
  }
  if (lane == 0) {
    int i0 = 0; float l0 = lg[0];
#pragma unroll
    for (int e = 1; e < 8; ++e) if (lg[e] > l0) { l0 = lg[e]; i0 = e; }
    int i1 = -1; float l1 = -1e30f;
#pragma unroll
    for (int e = 0; e < 8; ++e) if (e != i0 && lg[e] > l1) { l1 = lg[e]; i1 = e; }
    float w0 = 1.f / (1.f + __expf(l1 - l0));
    atomicAdd(&counts[i0], 1);
    atomicAdd(&counts[i1], 1);
    tk_idx[2 * t]     = i0;  tk_idx[2 * t + 1] = i1;
    tk_w[2 * t]       = w0;  tk_w[2 * t + 1]   = 1.f - w0;
  }
}

// offsets + compact (expert, m0) tile table: active slots contiguous from 0.
__global__ void offsets_k(const int* __restrict__ counts, int* __restrict__ offsets,
                          int* __restrict__ cursor,
                          int* __restrict__ slot_e, int* __restrict__ slot_m0) {
  if (threadIdx.x == 0) {
    int off = 0, s = 0;
    for (int e = 0; e < NEXP; ++e) {
      offsets[e] = off; cursor[e] = off;
      for (int m0 = 0; m0 < counts[e]; m0 += 128) { slot_e[s] = e; slot_m0[s] = m0; ++s; }
      off += counts[e];
    }
    for (; s < NSLOT; ++s) { slot_e[s] = -1; slot_m0[s] = 0; }
  }
}

__global__ __launch_bounds__(256) void scatter_k(const int* __restrict__ tk_idx,
    const float* __restrict__ tk_w, int* __restrict__ cursor,
    int* __restrict__ pair_token, float* __restrict__ pair_w, int* __restrict__ pair_pos) {
  int t = blockIdx.x * 256 + threadIdx.x;
#pragma unroll
  for (int k = 0; k < 2; ++k) {
    int e = tk_idx[2 * t + k];
    int pos = atomicAdd(&cursor[e], 1);
    pair_token[pos] = t;
    pair_w[pos] = tk_w[2 * t + k];
    pair_pos[2 * t + k] = pos;
  }
}

// ---------------- expert-sorted token rows: xs[p] = bf16(x[pair_token[p]]) ----------------
__global__ __launch_bounds__(256) void gatherx_k(const float* __restrict__ x,
    const int* __restrict__ pair_token, __hip_bfloat16* __restrict__ xs) {
  int p = blockIdx.x;
  int t = pair_token[p];
  const float* src = x + (size_t)t * E_DIM;
  __hip_bfloat16* dst = xs + (size_t)p * E_DIM;
  int i = threadIdx.x * 4;
  floatx4 v = *(const floatx4*)(src + i);
  union { __hip_bfloat16 h[4]; short4v s; } u;
#pragma unroll
  for (int j = 0; j < 4; ++j) u.h[j] = f2bf(v[j]);
  *(short4v*)(dst + i) = u.s;
}

// ------------- transpose + convert: in fp32 [R][C] -> out bf16 [Cp][outRS] -------------
__global__ __launch_bounds__(256) void tcvt_k(const float* __restrict__ in,
    __hip_bfloat16* __restrict__ out, int R, int C, int outRS,
    size_t inExpStride, size_t outExpStride) {
  __shared__ float tile[64 * 65];
  int e = blockIdx.z;
  const float* ip = in + inExpStride * e;
  __hip_bfloat16* op = out + outExpStride * e;
  int c0 = blockIdx.x * 64, r0 = blockIdx.y * 64;
#pragma unroll
  for (int i = 0; i < 16; ++i) {
    int idx = i * 256 + threadIdx.x;
    int rr = idx >> 6, cc = idx & 63;
    int gr = r0 + rr, gc = c0 + cc;
    tile[rr * 65 + cc] = (gr < R && gc < C) ? ip[(size_t)gr * C + gc] : 0.f;
  }
  __syncthreads();
#pragma unroll
  for (int i = 0; i < 2; ++i) {
    int idx = i * 256 + threadIdx.x;
    int cc = idx >> 3, rb = (idx & 7) * 8;
    union { __hip_bfloat16 h[8]; intx4 v; } u;
#pragma unroll
    for (int j = 0; j < 8; ++j) u.h[j] = f2bf(tile[(rb + j) * 65 + cc]);
    *(intx4*)(op + (size_t)(c0 + cc) * outRS + (r0 + rb)) = u.v;
  }
}

// ---------------- GEMM1: h = silu(xs@Wv+bv) * (xs@Wg+bg) ----------------
// 128m x 128n (dual B), BK=32, 3-buffer rotation with counted vmcnt (T3+T4):
// per K-step: STAGE(kt+2 -> buf[(c+2)%3]); ds_read+MFMA on buf[c];
// s_waitcnt vmcnt(6) (kt+1 landed, kt+2 stays in flight); raw s_barrier.
// Never drains vmcnt in the main loop. Swizzle key (row>>1)&3 (0-conflict, R4).
__global__ __launch_bounds__(256, 2) void gemm1_k(
    const __hip_bfloat16* __restrict__ xs,
    const int* __restrict__ counts, const int* __restrict__ offsets,
    const int* __restrict__ slot_e, const int* __restrict__ slot_m0,
    const float* __restrict__ bv, const float* __restrict__ bg,
    const __hip_bfloat16* __restrict__ WvT, const __hip_bfloat16* __restrict__ WgT,
    __hip_bfloat16* __restrict__ h) {
  int slot = blockIdx.y;
  int e = slot_e[slot];
  if (e < 0) return;
  int m0 = slot_m0[slot];
  int Me = counts[e], off = offsets[e];
  int n0 = blockIdx.x * 128;

  __shared__ __align__(16) __hip_bfloat16 sA[3 * BUFH];
  __shared__ __align__(16) __hip_bfloat16 sBv[3 * BUFH];
  __shared__ __align__(16) __hip_bfloat16 sBg[3 * BUFH];

  int tid = threadIdx.x;
  int wid = tid >> 6, lane = tid & 63;
  int wm = wid >> 1, wn = wid & 1;
  int q = lane >> 4, r = lane & 15;

  // fragment read offsets (halfs): row*32 + ((q ^ ((row>>1)&3))<<3)
  int csw = (q ^ ((r >> 1) & 3)) << 3;
  int aoff[4], boff[4];
#pragma unroll
  for (int mi = 0; mi < 4; ++mi) aoff[mi] = (wm * 64 + mi * 16 + r) * 32 + csw;
#pragma unroll
  for (int ni = 0; ni < 4; ++ni) boff[ni] = (wn * 64 + ni * 16 + r) * 32 + csw;

  // staging: 16 rows x 64B per gload; source chunk = (l&3) ^ ((l>>3)&3)
  int srow4   = lane >> 2;
  int schunk4 = (lane & 3) ^ ((lane >> 3) & 3);
  const __hip_bfloat16* gA = xs + (size_t)(off + m0 + wid * 16 + srow4) * E_DIM + schunk4 * 8;
  size_t wb = (size_t)e * ((size_t)HP * E_DIM);
  size_t browoff = wb + (size_t)(n0 + wid * 16 + srow4) * E_DIM + schunk4 * 8;
  const __hip_bfloat16* gv = WvT + browoff;
  const __hip_bfloat16* gg = WgT + browoff;

  floatx4 accv[4][4], accg[4][4];
  floatx4 zz = {0.f, 0.f, 0.f, 0.f};
#pragma unroll
  for (int mi = 0; mi < 4; ++mi)
#pragma unroll
    for (int ni = 0; ni < 4; ++ni) { accv[mi][ni] = zz; accg[mi][ni] = zz; }

#define G1_STAGE(C, KK)                                                         \
  {                                                                             \
    size_t _ko = (size_t)(KK) * 32;                                             \
    _Pragma("unroll")                                                           \
    for (int i = 0; i < 2; ++i) {                                               \
      gload16(gA + _ko + (size_t)i * 64 * E_DIM, &sA[(C) * BUFH + (wid + i * 4) * 512]);  \
      gload16(gv + _ko + (size_t)i * 64 * E_DIM, &sBv[(C) * BUFH + (wid + i * 4) * 512]); \
      gload16(gg + _ko + (size_t)i * 64 * E_DIM, &sBg[(C) * BUFH + (wid + i * 4) * 512]); \
    }                                                                           \
  }

#define G1_COMP(C)                                                              \
  {                                                                             \
    short8 av[4], b8v[4], b8g[4];                                               \
    _Pragma("unroll")                                                           \
    for (int mi = 0; mi < 4; ++mi)                                              \
      av[mi] = *(const short8*)(&sA[(C) * BUFH + aoff[mi]]);                    \
    _Pragma("unroll")                                                           \
    for (int ni = 0; ni < 4; ++ni) {                                            \
      b8v[ni] = *(const short8*)(&sBv[(C) * BUFH + boff[ni]]);                  \
      b8g[ni] = *(const short8*)(&sBg[(C) * BUFH + boff[ni]]);                  \
    }                                                                           \
    __builtin_amdgcn_s_setprio(1);                                              \
    _Pragma("unroll")                                                           \
    for (int ni = 0; ni < 4; ++ni)                                              \
      _Pragma("unroll")                                                         \
      for (int mi = 0; mi < 4; ++mi) {                                          \
        accv[mi][ni] = __builtin_amdgcn_mfma_f32_16x16x32_bf16(av[mi], b8v[ni], accv[mi][ni], 0, 0, 0); \
        accg[mi][ni] = __builtin_amdgcn_mfma_f32_16x16x32_bf16(av[mi], b8g[ni], accg[mi][ni], 0, 0, 0); \
      }                                                                         \
    __builtin_amdgcn_s_setprio(0);                                              \
  }

  // prologue: k0 -> buf0, k1 -> buf1; wait k0 landed (k1 stays in flight)
  G1_STAGE(0, 0);
  G1_STAGE(1, 1);
  VMC6; BAR;

  // main loop: NK = 32 k-tiles; triples keep buffer indices compile-time.
  for (int kt = 0; kt < 30; kt += 3) {
    G1_STAGE(2, kt + 2); G1_COMP(0); VMC6; BAR;
    G1_STAGE(0, kt + 3); G1_COMP(1); VMC6; BAR;
    G1_STAGE(1, kt + 4); G1_COMP(2); VMC6; BAR;
  }
  // tail: k30 (buf0), k31 (buf1)
  G1_COMP(0); VMC0; BAR;
  G1_COMP(1);

  // epilogue: silu(hv) * hg -> h (bf16)
  float bvv[4], bgv[4];
#pragma unroll
  for (int ni = 0; ni < 4; ++ni) {
    int n = n0 + wn * 64 + ni * 16 + r;
    bvv[ni] = (n < HDIM) ? bv[e * HDIM + n] : 0.f;
    bgv[ni] = (n < HDIM) ? bg[e * HDIM + n] : 0.f;
  }
#pragma unroll
  for (int mi = 0; mi < 4; ++mi) {
#pragma unroll
    for (int rr = 0; rr < 4; ++rr) {
      int m_loc = wm * 64 + mi * 16 + q * 4 + rr;
      int m = m0 + m_loc;
      if (m >= Me) continue;
      size_t hrow = (size_t)(off + m) * HP;
#pragma unroll
      for (int ni = 0; ni < 4; ++ni) {
        int n = n0 + wn * 64 + ni * 16 + r;
        float hv = accv[mi][ni][rr] + bvv[ni];
        float hg = accg[mi][ni][rr] + bgv[ni];
        float sgm = 1.f / (1.f + __expf(-hv));
        h[hrow + n] = f2bf(hv * sgm * hg);
      }
    }
  }
}

// ---------------- GEMM2: pair_out = h @ Wo + bo ----------------
// 128m x 128n, BK=32, same 3-buffer counted-vmcnt rotation (4 loads/STAGE).
__global__ __launch_bounds__(256, 2) void gemm2_k(
    const __hip_bfloat16* __restrict__ hb,
    const int* __restrict__ counts, const int* __restrict__ offsets,
    const int* __restrict__ slot_e, const int* __restrict__ slot_m0,
    const float* __restrict__ bo,
    const __hip_bfloat16* __restrict__ WoT,
    float* __restrict__ pout) {
  int slot = blockIdx.y;
  int e = slot_e[slot];
  if (e < 0) return;
  int m0 = slot_m0[slot];
  int Me = counts[e], off = offsets[e];
  int n0 = blockIdx.x * 128;

  __shared__ __align__(16) __hip_bfloat16 sA[3 * BUFH];
  __shared__ __align__(16) __hip_bfloat16 sB[3 * BUFH];

  int tid = threadIdx.x;
  int wid = tid >> 6, lane = tid & 63;
  int wm = wid >> 1, wn = wid & 1;
  int q = lane >> 4, r = lane & 15;

  int csw = (q ^ ((r >> 1) & 3)) << 3;
  int aoff[4], boff[4];
#pragma unroll
  for (int mi = 0; mi < 4; ++mi) aoff[mi] = (wm * 64 + mi * 16 + r) * 32 + csw;
#pragma unroll
  for (int ni = 0; ni < 4; ++ni) boff[ni] = (wn * 64 + ni * 16 + r) * 32 + csw;

  int srow4   = lane >> 2;
  int schunk4 = (lane & 3) ^ ((lane >> 3) & 3);
  const __hip_bfloat16* gA = hb + (size_t)(off + m0 + wid * 16 + srow4) * HP + schunk4 * 8;
  const __hip_bfloat16* gB = WoT + (size_t)e * ((size_t)E_DIM * HP) +
                             (size_t)(n0 + wid * 16 + srow4) * HP + schunk4 * 8;

  floatx4 acc[4][4];
  floatx4 zz = {0.f, 0.f, 0.f, 0.f};
#pragma unroll
  for (int mi = 0; mi < 4; ++mi)
#pragma unroll
    for (int ni = 0; ni < 4; ++ni) acc[mi][ni] = zz;

#define G2_STAGE(C, KK)                                                         \
  {                                                                             \
    size_t _ko = (size_t)(KK) * 32;                                             \
    _Pragma("unroll")                                                           \
    for (int i = 0; i < 2; ++i) {                                               \
      gload16(gA + _ko + (size_t)i * 64 * HP, &sA[(C) * BUFH + (wid + i * 4) * 512]); \
      gload16(gB + _ko + (size_t)i * 64 * HP, &sB[(C) * BUFH + (wid + i * 4) * 512]); \
    }                                                                           \
  }

#define G2_COMP(C)                                                              \
  {                                                                             \
    short8 av[4], b8[4];                                                        \
    _Pragma("unroll")                                                           \
    for (int mi = 0; mi < 4; ++mi)                                              \
      av[mi] = *(const short8*)(&sA[(C) * BUFH + aoff[mi]]);                    \
    _Pragma("unroll")                                                           \
    for (int ni = 0; ni < 4; ++ni)                                              \
      b8[ni] = *(const short8*)(&sB[(C) * BUFH + boff[ni]]);                    \
    __builtin_amdgcn_s_setprio(1);                                              \
    _Pragma("unroll")                                                           \
    for (int ni = 0; ni < 4; ++ni)                                              \
      _Pragma("unroll")                                                         \
      for (int mi = 0; mi < 4; ++mi)                                            \
        acc[mi][ni] = __builtin_amdgcn_mfma_f32_16x16x32_bf16(av[mi], b8[ni], acc[mi][ni], 0, 0, 0); \
    __builtin_amdgcn_s_setprio(0);                                              \
  }

  // NK = HP/32 = 88 k-tiles.
  G2_STAGE(0, 0);
  G2_STAGE(1, 1);
  VMC4; BAR;

  for (int kt = 0; kt < 84; kt += 3) {
    G2_STAGE(2, kt + 2); G2_COMP(0); VMC4; BAR;
    G2_STAGE(0, kt + 3); G2_COMP(1); VMC4; BAR;
    G2_STAGE(1, kt + 4); G2_COMP(2); VMC4; BAR;
  }
  // tail: k84..k87 (c = 0,1,2,0)
  G2_STAGE(2, 86); G2_COMP(0); VMC4; BAR;
  G2_STAGE(0, 87); G2_COMP(1); VMC4; BAR;
  G2_COMP(2); VMC0; BAR;
  G2_COMP(0);

#pragma unroll
  for (int mi = 0; mi < 4; ++mi) {
#pragma unroll
    for (int rr = 0; rr < 4; ++rr) {
      int m_loc = wm * 64 + mi * 16 + q * 4 + rr;
      int m = m0 + m_loc;
      if (m >= Me) continue;
      size_t orow = (size_t)(off + m) * E_DIM;
#pragma unroll
      for (int ni = 0; ni < 4; ++ni) {
        int n = n0 + wn * 64 + ni * 16 + r;
        pout[orow + n] = acc[mi][ni][rr] + bo[e * E_DIM + n];
      }
    }
  }
}

// ---------------- combine + residual + LayerNorm ----------------
__global__ __launch_bounds__(256) void ln_k(const float* __restrict__ x,
    const float* __restrict__ pout, const int* __restrict__ pair_pos,
    const float* __restrict__ pair_w, const float* __restrict__ ln_g,
    const float* __restrict__ ln_b, float* __restrict__ out) {
  int t = blockIdx.x, tid = threadIdx.x;
  int p0 = pair_pos[2 * t], p1 = pair_pos[2 * t + 1];
  float w0 = pair_w[p0], w1 = pair_w[p1];
  const float* xr = x + (size_t)t * E_DIM;
  const float* r0 = pout + (size_t)p0 * E_DIM;
  const float* r1 = pout + (size_t)p1 * E_DIM;
  float y[4];
  float s = 0.f, ss = 0.f;
#pragma unroll
  for (int i = 0; i < 4; ++i) {
    int e = tid + 256 * i;
    y[i] = xr[e] + w0 * r0[e] + w1 * r1[e];
    s += y[i];
    ss += y[i] * y[i];
  }
#pragma unroll
  for (int o = 32; o; o >>= 1) { s += __shfl_xor(s, o, 64); ss += __shfl_xor(ss, o, 64); }
  __shared__ float red[8];
  int wid = tid >> 6, lane = tid & 63;
  if (lane == 0) { red[wid] = s; red[4 + wid] = ss; }
  __syncthreads();
  s  = red[0] + red[1] + red[2] + red[3];
  ss = red[4] + red[5] + red[6] + red[7];
  float mu = s * (1.f / E_DIM);
  float var = ss * (1.f / E_DIM) - mu * mu;
  float rs = rsqrtf(var + LN_EPS);
#pragma unroll
  for (int i = 0; i < 4; ++i) {
    int e = tid + 256 * i;
    out[(size_t)t * E_DIM + e] = ln_g[e] * (y[i] - mu) * rs + ln_b[e];
  }
}

extern "C" void kernel_launch(void* const* d_in, const int* in_sizes, int n_in,
                              void* d_out, int out_size, void* d_ws, size_t ws_size,
                              hipStream_t stream) {
  const float* x    = (const float*)d_in[0];
  const float* Wr   = (const float*)d_in[1];
  const float* Wv   = (const float*)d_in[2];
  const float* bv   = (const float*)d_in[3];
  const float* Wg   = (const float*)d_in[4];
  const float* bg   = (const float*)d_in[5];
  const float* Wo   = (const float*)d_in[6];
  const float* bo   = (const float*)d_in[7];
  const float* ln_g = (const float*)d_in[8];
  const float* ln_b = (const float*)d_in[9];
  float* out = (float*)d_out;

  char* ws = (char*)d_ws;
  size_t off = 0;
  auto alloc = [&](size_t bytes) -> void* {
    void* p = ws + off;
    off = (off + bytes + 255) & ~(size_t)255;
    return p;
  };
  int*   counts     = (int*)alloc(32);
  int*   cursor     = (int*)alloc(32);
  int*   offsets    = (int*)alloc(32);
  int*   slot_e     = (int*)alloc(NSLOT * 4);
  int*   slot_m0    = (int*)alloc(NSLOT * 4);
  int*   tk_idx     = (int*)alloc((size_t)NTOK * 2 * 4);
  float* tk_w       = (float*)alloc((size_t)NTOK * 2 * 4);
  int*   pair_token = (int*)alloc((size_t)NPAIR * 4);
  float* pair_w     = (float*)alloc((size_t)NPAIR * 4);
  int*   pair_pos   = (int*)alloc((size_t)NPAIR * 4);
  __hip_bfloat16* xs   = (__hip_bfloat16*)alloc((size_t)(NPAIR + 128) * E_DIM * 2);
  __hip_bfloat16* hbuf = (__hip_bfloat16*)alloc((size_t)(NPAIR + 128) * HP * 2);
  float* pout = (float*)alloc((size_t)NPAIR * E_DIM * 4);

  size_t welems = (size_t)NEXP * HP * E_DIM;
  __hip_bfloat16* WvT = (__hip_bfloat16*)alloc(welems * 2);
  __hip_bfloat16* WgT = (__hip_bfloat16*)alloc(welems * 2);
  __hip_bfloat16* WoT = (__hip_bfloat16*)alloc(welems * 2);

  hipMemsetAsync(d_ws, 0, 1024, stream);  // counts / cursor / offsets / slots

  router_k<<<NTOK / 4, 256, 0, stream>>>(x, Wr, counts, tk_idx, tk_w);
  offsets_k<<<1, 64, 0, stream>>>(counts, offsets, cursor, slot_e, slot_m0);
  scatter_k<<<NTOK / 256, 256, 0, stream>>>(tk_idx, tk_w, cursor, pair_token, pair_w, pair_pos);
  gatherx_k<<<NPAIR, 256, 0, stream>>>(x, pair_token, xs);

  tcvt_k<<<dim3(HP / 64, E_DIM / 64, NEXP), 256, 0, stream>>>(
      Wv, WvT, E_DIM, HDIM, E_DIM, (size_t)E_DIM * HDIM, (size_t)HP * E_DIM);
  tcvt_k<<<dim3(HP / 64, E_DIM / 64, NEXP), 256, 0, stream>>>(
      Wg, WgT, E_DIM, HDIM, E_DIM, (size_t)E_DIM * HDIM, (size_t)HP * E_DIM);
  tcvt_k<<<dim3(E_DIM / 64, HP / 64, NEXP), 256, 0, stream>>>(
      Wo, WoT, HDIM, E_DIM, HP, (size_t)HDIM * E_DIM, (size_t)E_DIM * HP);

  gemm1_k<<<dim3(HP / 128, NSLOT), 256, 0, stream>>>(
      xs, counts, offsets, slot_e, slot_m0, bv, bg, WvT, WgT, hbuf);
  gemm2_k<<<dim3(E_DIM / 128, NSLOT), 256, 0, stream>>>(
      hbuf, counts, offsets, slot_e, slot_m0, bo, WoT, pout);

  ln_k<<<NTOK, 256, 0, stream>>>(x, pout, pair_pos, pair_w, ln_g, ln_b, out);
}